// Round 6
// baseline (334.111 us; speedup 1.0000x reference)
//
#include <hip/hip_runtime.h>
#include <hip/hip_bf16.h>

// B=4, Q=K=1024, C=512, H=8, HD=64, OUT=512
// d_out = [output (4*1024*512 f32) | logits_update (4*8*1024*1024 f32)]

typedef float f32x4 __attribute__((ext_vector_type(4)));
typedef __bf16 bf16x8 __attribute__((ext_vector_type(8)));
typedef __bf16 bf16x4 __attribute__((ext_vector_type(4)));

static __device__ __forceinline__ __bf16 f2bf(float x) {
    union { float f; unsigned int u; } c; c.f = x;
    unsigned int r = (c.u + 0x7fffu + ((c.u >> 16) & 1u)) >> 16;
    union { unsigned short s; __bf16 b; } o; o.s = (unsigned short)r;
    return o.b;
}

// async global->LDS, 16B per lane; LDS dest = wave-uniform base + lane*16
static __device__ __forceinline__ void async16(const void* g, void* l) {
    __builtin_amdgcn_global_load_lds(
        (const __attribute__((address_space(1))) void*)g,
        (__attribute__((address_space(3))) void*)l, 16, 0, 0);
}

// ---------------------------------------------------------------------------
// Cast q_data/m_data f32 -> bf16, vectorized (8 elem/thread each).
// ---------------------------------------------------------------------------
__global__ __launch_bounds__(256) void cast_data(
    const float* __restrict__ qd, const float* __restrict__ md,
    __bf16* __restrict__ qdb, __bf16* __restrict__ mdb)
{
    const int i = blockIdx.x * 256 + threadIdx.x;   // 0..262143
    const f32x4* q4 = (const f32x4*)qd;
    const f32x4* m4 = (const f32x4*)md;
    f32x4 a = q4[2 * i], b = q4[2 * i + 1];
    bf16x8 o;
#pragma unroll
    for (int j = 0; j < 4; j++) { o[j] = f2bf(a[j]); o[4 + j] = f2bf(b[j]); }
    *(bf16x8*)&qdb[i * 8] = o;
    a = m4[2 * i]; b = m4[2 * i + 1];
#pragma unroll
    for (int j = 0; j < 4; j++) { o[j] = f2bf(a[j]); o[4 + j] = f2bf(b[j]); }
    *(bf16x8*)&mdb[i * 8] = o;
}

// ---------------------------------------------------------------------------
// Tiled transpose+cast of the five 512x512 weight matrices (z selects).
// out[n*512+a] = in[a*512+n] * scale  (qw gets 1/8 folded in)
// ---------------------------------------------------------------------------
__global__ __launch_bounds__(256) void transpose_cast(
    const float* __restrict__ qw, const float* __restrict__ kw,
    const float* __restrict__ vw, const float* __restrict__ gw,
    const float* __restrict__ ow,
    __bf16* __restrict__ qwt, __bf16* __restrict__ kwt,
    __bf16* __restrict__ vwt, __bf16* __restrict__ gwt,
    __bf16* __restrict__ owt)
{
    __shared__ float tile[64][65];
    const int z = blockIdx.z;
    const float* src = (z == 0) ? qw : (z == 1) ? kw : (z == 2) ? vw : (z == 3) ? gw : ow;
    __bf16* dst = (z == 0) ? qwt : (z == 1) ? kwt : (z == 2) ? vwt : (z == 3) ? gwt : owt;
    const float scale = (z == 0) ? 0.125f : 1.0f;
    const int a0 = blockIdx.x * 64, n0 = blockIdx.y * 64;
    const int t = threadIdx.x, tr = t >> 4, tc = (t & 15) * 4;
#pragma unroll
    for (int ii = 0; ii < 4; ii++) {
        f32x4 v = *(const f32x4*)&src[(a0 + tr + 16 * ii) * 512 + n0 + tc];
#pragma unroll
        for (int j = 0; j < 4; j++) tile[tr + 16 * ii][tc + j] = v[j] * scale;
    }
    __syncthreads();
#pragma unroll
    for (int ii = 0; ii < 4; ii++) {
        const int nr = tr + 16 * ii;
        bf16x4 o;
#pragma unroll
        for (int j = 0; j < 4; j++) o[j] = f2bf(tile[tc + j][nr]);
        *(bf16x4*)&dst[(n0 + nr) * 512 + a0 + tc] = o;
    }
}

// ---------------------------------------------------------------------------
// 64x64-tile bf16 GEMM core, K=512 (kept for out_gemm where grid is small).
// ---------------------------------------------------------------------------
static __device__ __forceinline__ void gemm_core64(
    const __bf16* __restrict__ A, const __bf16* __restrict__ Bt,
    __bf16* As, __bf16* Bs, int m0, int n0, int t, f32x4 acc[4])
{
    const int w = t >> 6, quad = (t >> 4) & 3, col = t & 15;
    const int sr = t >> 2, sc = (t & 3) * 8;
    for (int kk = 0; kk < 512; kk += 32) {
        __syncthreads();
        async16(&A[(m0 + sr) * 512 + kk + sc], &As[w * 512]);
        async16(&Bt[(n0 + sr) * 512 + kk + sc], &Bs[w * 512]);
        __syncthreads();
        bf16x8 af = *(const bf16x8*)&As[(w * 16 + col) * 32 + quad * 8];
#pragma unroll
        for (int ns = 0; ns < 4; ns++) {
            bf16x8 bfr = *(const bf16x8*)&Bs[(ns * 16 + col) * 32 + quad * 8];
            acc[ns] = __builtin_amdgcn_mfma_f32_16x16x32_bf16(af, bfr, acc[ns], 0, 0, 0);
        }
    }
}

// ---------------------------------------------------------------------------
// 128x128-tile bf16 GEMM core, K=512 (m97 structure).
// ---------------------------------------------------------------------------
static __device__ __forceinline__ void gemm_core128(
    const __bf16* __restrict__ A, const __bf16* __restrict__ Bt,
    __bf16* As, __bf16* Bs, int m0, int n0, int t, f32x4 acc[4][4])
{
    const int w = t >> 6, quad = (t >> 4) & 3, col = t & 15;
    const int wr = (w >> 1) * 64, wc = (w & 1) * 64;
    const int sr = t >> 2, sc = (t & 3) * 8;   // staging: 64 rows x 4 chunks per call
    for (int kk = 0; kk < 512; kk += 32) {
        __syncthreads();
        async16(&A[(m0 + sr) * 512 + kk + sc], &As[w * 512]);
        async16(&A[(m0 + 64 + sr) * 512 + kk + sc], &As[2048 + w * 512]);
        async16(&Bt[(n0 + sr) * 512 + kk + sc], &Bs[w * 512]);
        async16(&Bt[(n0 + 64 + sr) * 512 + kk + sc], &Bs[2048 + w * 512]);
        __syncthreads();
        bf16x8 af[4], bfr[4];
#pragma unroll
        for (int i = 0; i < 4; i++)
            af[i] = *(const bf16x8*)&As[(wr + i * 16 + col) * 32 + quad * 8];
#pragma unroll
        for (int i = 0; i < 4; i++)
            bfr[i] = *(const bf16x8*)&Bs[(wc + i * 16 + col) * 32 + quad * 8];
#pragma unroll
        for (int mi = 0; mi < 4; mi++)
#pragma unroll
            for (int ni = 0; ni < 4; ni++)
                acc[mi][ni] = __builtin_amdgcn_mfma_f32_16x16x32_bf16(
                    af[mi], bfr[ni], acc[mi][ni], 0, 0, 0);
    }
}

// ---------------------------------------------------------------------------
// Merged projection GEMMs (128x128 tiles): z=0 q (b,h,pos,c); z=1 k;
// z=2 v transposed (b,h,c,pos); z=3 gate sigmoid (m,512).
// ---------------------------------------------------------------------------
__global__ __launch_bounds__(256) void proj_gemm(
    const __bf16* __restrict__ qdb, const __bf16* __restrict__ mdb,
    const __bf16* __restrict__ qwt, const __bf16* __restrict__ kwt,
    const __bf16* __restrict__ vwt, const __bf16* __restrict__ gwt,
    __bf16* __restrict__ qbuf, __bf16* __restrict__ kbuf,
    __bf16* __restrict__ vt, __bf16* __restrict__ gate,
    const float* __restrict__ gb)
{
    __shared__ __attribute__((aligned(16))) __bf16 As[4096];
    __shared__ __attribute__((aligned(16))) __bf16 Bs[4096];
    const int z = blockIdx.z;
    const __bf16* A = (z == 0 || z == 3) ? qdb : mdb;
    const __bf16* Bt = (z == 0) ? qwt : (z == 1) ? kwt : (z == 2) ? vwt : gwt;
    const int m0 = blockIdx.x * 128, n0 = blockIdx.y * 128;
    f32x4 acc[4][4];
#pragma unroll
    for (int i = 0; i < 4; i++)
#pragma unroll
        for (int j = 0; j < 4; j++) acc[i][j] = (f32x4){0.f, 0.f, 0.f, 0.f};
    gemm_core128(A, Bt, As, Bs, m0, n0, threadIdx.x, acc);

    const int t = threadIdx.x, w = t >> 6, quad = (t >> 4) & 3, col = t & 15;
    const int wr = (w >> 1) * 64, wc = (w & 1) * 64;
#pragma unroll
    for (int mi = 0; mi < 4; mi++) {
#pragma unroll
        for (int ni = 0; ni < 4; ni++) {
            const int ncol = n0 + wc + ni * 16 + col;
#pragma unroll
            for (int r = 0; r < 4; r++) {
                const int m = m0 + wr + mi * 16 + quad * 4 + r;
                const float v = acc[mi][ni][r];
                if (z <= 1) {
                    int b = m >> 10, pos = m & 1023, hh = ncol >> 6, c = ncol & 63;
                    __bf16* o = z ? kbuf : qbuf;
                    o[(((b * 8 + hh) * 1024 + pos) << 6) + c] = f2bf(v);
                } else if (z == 2) {
                    int b = m >> 10, pos = m & 1023, hh = ncol >> 6, c = ncol & 63;
                    vt[((((b * 8 + hh) << 6) + c) << 10) + pos] = f2bf(v);
                } else {
                    float g = 1.0f / (1.0f + __expf(-(v + gb[ncol])));
                    gate[m * 512 + ncol] = f2bf(g);
                }
            }
        }
    }
}

// ---------------------------------------------------------------------------
// Output GEMM: out[m,n] = wavg @ ow_t + output_b  (f32 out)
// ---------------------------------------------------------------------------
__global__ __launch_bounds__(256) void out_gemm(
    const __bf16* __restrict__ A, const __bf16* __restrict__ Bt,
    float* __restrict__ outp, const float* __restrict__ bvec)
{
    __shared__ __attribute__((aligned(16))) __bf16 As[2048];
    __shared__ __attribute__((aligned(16))) __bf16 Bs[2048];
    const int m0 = blockIdx.x * 64, n0 = blockIdx.y * 64;
    f32x4 acc[4];
#pragma unroll
    for (int i = 0; i < 4; i++) acc[i] = (f32x4){0.f, 0.f, 0.f, 0.f};
    gemm_core64(A, Bt, As, Bs, m0, n0, threadIdx.x, acc);

    const int t = threadIdx.x, w = t >> 6, quad = (t >> 4) & 3, col = t & 15;
    const int mrow0 = m0 + w * 16 + quad * 4;
#pragma unroll
    for (int ns = 0; ns < 4; ns++) {
        const int ncol = n0 + ns * 16 + col;
#pragma unroll
        for (int r = 0; r < 4; r++)
            outp[(mrow0 + r) * 512 + ncol] = acc[ns][r] + bvec[ncol];
    }
}

// ---------------------------------------------------------------------------
// Kernel 1 of split attention: S = Q @ K^T, raw logits streamed to d_out.
// R3's attn minus softmax/PV: swapped MFMA (S^T frags) -> f32x4 NT stores
// along the key dim. Store-BW-bound by design (131 MB writes).
// ---------------------------------------------------------------------------
__global__ __launch_bounds__(256) void qk_gemm(
    const __bf16* __restrict__ qb, const __bf16* __restrict__ kb,
    float* __restrict__ logits_out)
{
    __shared__ __attribute__((aligned(16))) __bf16 ks[2][4096];
    const int bh = blockIdx.y;
    const int q0 = blockIdx.x * 64;
    const int t = threadIdx.x, lane = t & 63, w = t >> 6;
    const int quad = lane >> 4, col = lane & 15;

    const __bf16* kg = kb + bh * 65536;
    float* lg = logits_out + (size_t)(bh * 1024 + q0) * 1024;

    const int r0 = t >> 3, c0 = t & 7;
    const int sw = ((c0 ^ (r0 & 7)) << 3);
    async16(&kg[r0 * 64 + sw], &ks[0][w * 512]);
    async16(&kg[(r0 + 32) * 64 + sw], &ks[0][2048 + w * 512]);

    const __bf16* qrow = qb + (size_t)(bh * 1024 + q0 + w * 16 + col) * 64;
    const bf16x8 af0 = *(const bf16x8*)&qrow[quad * 8];
    const bf16x8 af1 = *(const bf16x8*)&qrow[32 + quad * 8];
    const int sw0 = ((quad ^ (col & 7)) << 3);
    const int sw1 = (((quad + 4) ^ (col & 7)) << 3);

    __syncthreads();
    for (int kbi = 0; kbi < 16; kbi++) {
        const int cur = kbi & 1;
        if (kbi < 15) {
            const __bf16* kgn = kg + (kbi + 1) * 4096;
            async16(&kgn[r0 * 64 + sw], &ks[cur ^ 1][w * 512]);
            async16(&kgn[(r0 + 32) * 64 + sw], &ks[cur ^ 1][2048 + w * 512]);
        }
        __builtin_amdgcn_sched_barrier(0);
        const __bf16* kc = ks[cur];
        f32x4 s[4];
#pragma unroll
        for (int i = 0; i < 4; i++) s[i] = (f32x4){0.f, 0.f, 0.f, 0.f};
        __builtin_amdgcn_s_setprio(1);
#pragma unroll
        for (int ns = 0; ns < 4; ns++) {
            bf16x8 b0 = *(const bf16x8*)&kc[(ns * 16 + col) * 64 + sw0];
            s[ns] = __builtin_amdgcn_mfma_f32_16x16x32_bf16(b0, af0, s[ns], 0, 0, 0);
            bf16x8 b1 = *(const bf16x8*)&kc[(ns * 16 + col) * 64 + sw1];
            s[ns] = __builtin_amdgcn_mfma_f32_16x16x32_bf16(b1, af1, s[ns], 0, 0, 0);
        }
        __builtin_amdgcn_s_setprio(0);
        float* lrow = lg + (w * 16 + col) * 1024 + kbi * 64;
#pragma unroll
        for (int ns = 0; ns < 4; ns++)
            __builtin_nontemporal_store(s[ns], (f32x4*)&lrow[ns * 16 + quad * 4]);
        if (kbi < 15) {
            // counted barrier: newest 4 VMEM = this iter's stores; waiting to 4
            // drains the 2 prefetch global_load_lds. Stores stream on.
            asm volatile("s_waitcnt lgkmcnt(0)" ::: "memory");
            asm volatile("s_waitcnt vmcnt(4)" ::: "memory");
            __builtin_amdgcn_sched_barrier(0);
            __builtin_amdgcn_s_barrier();
            __builtin_amdgcn_sched_barrier(0);
        }
    }
}

// ---------------------------------------------------------------------------
// Kernel 2 of split attention: read logits back (L3-hot), p=exp(l+bias+nb),
// O = P@V, gate, wout. P built entirely in registers (A-frag = 8 consecutive
// f32 of a logits row per lane) -> no P LDS, no QK MFMAs. Per-wave-private
// V staging (4KB tiles, XOR-swizzled) -> ZERO barriers in the loop; only
// wave-local counted vmcnt/lgkmcnt. 2 waves/block = K-halves, merged once.
// 4096 waves -> 16 waves/CU (50% occ). LDS 20KB -> 8 blocks/CU.
// ---------------------------------------------------------------------------
__global__ __launch_bounds__(128, 4) void pv_kernel(
    const float* __restrict__ logits, const float* __restrict__ bias,
    const float* __restrict__ nb, const __bf16* __restrict__ vt,
    const __bf16* __restrict__ gate, __bf16* __restrict__ wout)
{
    __shared__ __attribute__((aligned(16))) __bf16 vsl[2][2][2048]; // [wave][buf][64d x 32k]
    __shared__ __attribute__((aligned(16))) float bs[1024];

    const int bh = blockIdx.y, b = bh >> 3, h = bh & 7;
    const int q0 = blockIdx.x * 16;
    const int t = threadIdx.x, lane = t & 63, w = t >> 6;   // w = key-half
    const int quad = lane >> 4, col = lane & 15;
    const int kh = w;

    const __bf16* vg = vt + bh * 65536;                     // [d][key=1024]
    const float* lgr = logits + (size_t)(bh * 1024 + q0 + col) * 1024 + kh * 512;
    const float* nbp = nb + (size_t)(h * 1024 + q0 + col) * 1024 + kh * 512;
    const float* bg = bias + b * 1024;

    // stage bias (4KB) once: 2 waves x 2 calls x 64 lanes x 16B
    async16(&bg[w * 256 + lane * 4], (char*)bs + w * 1024);
    async16(&bg[512 + w * 256 + lane * 4], (char*)bs + 2048 + w * 1024);

    f32x4 o_acc[4];
#pragma unroll
    for (int i = 0; i < 4; i++) o_acc[i] = (f32x4){0.f, 0.f, 0.f, 0.f};
    float lsum = 0.f;

    // wave-private V tile prefetch: 64d x 32k, XOR-swizzled chunks
    auto PFV = [&](int kt) {
        const __bf16* src = vg + kh * 512 + kt * 32;
        __bf16* dst = &vsl[w][kt & 1][0];
#pragma unroll
        for (int c = 0; c < 4; c++) {
            const int row = c * 16 + (lane >> 2);
            const int slot = lane & 3;
            async16(&src[row * 1024 + ((slot ^ (row & 3)) << 3)], dst + c * 512);
        }
    };
    auto LOADL = [&](int kt, f32x4 L[2], f32x4 N[2]) {
        const float* lp = lgr + kt * 32;
        const float* np = nbp + kt * 32;
        L[0] = *(const f32x4*)&lp[quad * 8];
        L[1] = *(const f32x4*)&lp[quad * 8 + 4];
        N[0] = *(const f32x4*)&np[quad * 8];
        N[1] = *(const f32x4*)&np[quad * 8 + 4];
    };
    auto STEP = [&](int kt, const f32x4 L[2], const f32x4 N[2]) {
        const f32x4 bv0 = *(const f32x4*)&bs[kh * 512 + kt * 32 + quad * 8];
        const f32x4 bv1 = *(const f32x4*)&bs[kh * 512 + kt * 32 + quad * 8 + 4];
        bf16x8 pf;
#pragma unroll
        for (int j = 0; j < 4; j++) {
            float p = __expf(L[0][j] + bv0[j] + N[0][j]);
            lsum += p; pf[j] = f2bf(p);
        }
#pragma unroll
        for (int j = 0; j < 4; j++) {
            float p = __expf(L[1][j] + bv1[j] + N[1][j]);
            lsum += p; pf[4 + j] = f2bf(p);
        }
        const __bf16* vc = &vsl[w][kt & 1][0];
        __builtin_amdgcn_s_setprio(1);
#pragma unroll
        for (int ns = 0; ns < 4; ns++) {
            const int row = ns * 16 + col;
            bf16x8 vb = *(const bf16x8*)&vc[row * 32 + ((quad ^ (row & 3)) << 3)];
            o_acc[ns] = __builtin_amdgcn_mfma_f32_16x16x32_bf16(pf, vb, o_acc[ns], 0, 0, 0);
        }
        __builtin_amdgcn_s_setprio(0);
    };

    __syncthreads();    // bias staged (full drain, once)

    f32x4 La[2], Na[2], Lb[2], Nb[2];
    PFV(0); LOADL(0, La, Na);
#pragma unroll
    for (int kt = 0; kt < 16; kt += 2) {
        PFV(kt + 1); LOADL(kt + 1, Lb, Nb);
        // wait PFV(kt): newest 8 VMEM = {LOADL(kt+1), PFV(kt+1)}
        asm volatile("s_waitcnt vmcnt(8)" ::: "memory");
        STEP(kt, La, Na);
        // buf (kt&1) ds reads done before overwrite by PFV(kt+2)
        asm volatile("s_waitcnt lgkmcnt(0)" ::: "memory");
        __builtin_amdgcn_sched_barrier(0);
        if (kt + 2 < 16) {
            PFV(kt + 2); LOADL(kt + 2, La, Na);
            asm volatile("s_waitcnt vmcnt(8)" ::: "memory");   // PFV(kt+1) done
        } else {
            asm volatile("s_waitcnt vmcnt(4)" ::: "memory");   // PFV(15) done
        }
        STEP(kt + 1, Lb, Nb);
        if (kt + 2 < 16) {
            asm volatile("s_waitcnt lgkmcnt(0)" ::: "memory"); // buf ((kt+1)&1) reads done
            __builtin_amdgcn_sched_barrier(0);
        }
    }

    // merge the two key-halves (one barrier pair, end only)
    __syncthreads();
    float* ored = (float*)vsl;          // 16q x 64d f32 = 4KB (vsl dead)
    float* lred = ored + 1024;
    lsum += __shfl_xor(lsum, 16, 64);
    lsum += __shfl_xor(lsum, 32, 64);
    if (w == 1) {
#pragma unroll
        for (int ns = 0; ns < 4; ns++)
#pragma unroll
            for (int r = 0; r < 4; r++)
                ored[(quad * 4 + r) * 64 + ns * 16 + col] = o_acc[ns][r];
        if (lane < 16) lred[lane] = lsum;
    }
    __syncthreads();
    if (w == 0) {
        const float inv = 1.0f / (lsum + lred[col]);   // valid for q = col
        float invr[4];
#pragma unroll
        for (int r = 0; r < 4; r++) invr[r] = __shfl(inv, quad * 4 + r, 64);
#pragma unroll
        for (int ns = 0; ns < 4; ns++) {
            const int c = ns * 16 + col;
#pragma unroll
            for (int r = 0; r < 4; r++) {
                const int pos = q0 + quad * 4 + r;
                float ov = (o_acc[ns][r] + ored[(quad * 4 + r) * 64 + c]) * invr[r];
                float gv = (float)gate[(b * 1024 + pos) * 512 + h * 64 + c];
                wout[(b * 1024 + pos) * 512 + h * 64 + c] = f2bf(ov * gv);
            }
        }
    }
}

// ---------------------------------------------------------------------------
extern "C" void kernel_launch(void* const* d_in, const int* in_sizes, int n_in,
                              void* d_out, int out_size, void* d_ws, size_t ws_size,
                              hipStream_t stream) {
    (void)in_sizes; (void)n_in; (void)out_size; (void)ws_size;
    const float* q_data   = (const float*)d_in[0];
    const float* m_data   = (const float*)d_in[1];
    const float* bias     = (const float*)d_in[2];
    const float* nbb      = (const float*)d_in[3];
    const float* query_w  = (const float*)d_in[4];
    const float* key_w    = (const float*)d_in[5];
    const float* value_w  = (const float*)d_in[6];
    const float* gating_w = (const float*)d_in[7];
    const float* gating_b = (const float*)d_in[8];
    const float* output_w = (const float*)d_in[9];
    const float* output_b = (const float*)d_in[10];

    char* ws = (char*)d_ws;
    __bf16* qd_b  = (__bf16*)(ws + 0);         // 4 MiB (reused as wavg later)
    __bf16* md_b  = (__bf16*)(ws + 4194304);   // 4 MiB
    __bf16* qw_t  = (__bf16*)(ws + 8388608);   // 512 KiB each
    __bf16* kw_t  = (__bf16*)(ws + 8912896);
    __bf16* vw_t  = (__bf16*)(ws + 9437184);
    __bf16* gw_t  = (__bf16*)(ws + 9961472);
    __bf16* ow_t  = (__bf16*)(ws + 10485760);
    __bf16* q_buf = (__bf16*)(ws + 11010048);  // 4 MiB (b,h,pos,c)
    __bf16* k_buf = (__bf16*)(ws + 15204352);  // 4 MiB (b,h,pos,c)
    __bf16* v_t   = (__bf16*)(ws + 19398656);  // 4 MiB (b,h,c,pos)
    __bf16* gate  = (__bf16*)(ws + 23592960);  // 4 MiB (m,512)
    __bf16* wavg  = (__bf16*)(ws + 0);         // overlays qd_b (dead by then)

    float* outp = (float*)d_out;
    float* logits = outp + (4 * 1024 * 512);

    cast_data<<<dim3(1024), dim3(256), 0, stream>>>(q_data, m_data, qd_b, md_b);
    transpose_cast<<<dim3(8, 8, 5), dim3(256), 0, stream>>>(
        query_w, key_w, value_w, gating_w, output_w, qw_t, kw_t, vw_t, gw_t, ow_t);
    proj_gemm<<<dim3(32, 4, 4), dim3(256), 0, stream>>>(
        qd_b, md_b, qw_t, kw_t, vw_t, gw_t, q_buf, k_buf, v_t, gate, gating_b);
    qk_gemm<<<dim3(16, 32), dim3(256), 0, stream>>>(q_buf, k_buf, logits);
    pv_kernel<<<dim3(64, 32), dim3(128), 0, stream>>>(
        logits, bias, nbb, v_t, gate, wavg);
    out_gemm<<<dim3(64, 8), dim3(256), 0, stream>>>(wavg, ow_t, outp, output_b);
}

// Round 7
// 278.612 us; speedup vs baseline: 1.1992x; 1.1992x over previous
//
#include <hip/hip_runtime.h>
#include <hip/hip_bf16.h>

// B=4, Q=K=1024, C=512, H=8, HD=64, OUT=512
// d_out = [output (4*1024*512 f32) | logits_update (4*8*1024*1024 f32)]

typedef float f32x4 __attribute__((ext_vector_type(4)));
typedef __bf16 bf16x8 __attribute__((ext_vector_type(8)));
typedef __bf16 bf16x4 __attribute__((ext_vector_type(4)));

static __device__ __forceinline__ __bf16 f2bf(float x) {
    union { float f; unsigned int u; } c; c.f = x;
    unsigned int r = (c.u + 0x7fffu + ((c.u >> 16) & 1u)) >> 16;
    union { unsigned short s; __bf16 b; } o; o.s = (unsigned short)r;
    return o.b;
}

// async global->LDS, 16B per lane; LDS dest = wave-uniform base + lane*16
static __device__ __forceinline__ void async16(const void* g, void* l) {
    __builtin_amdgcn_global_load_lds(
        (const __attribute__((address_space(1))) void*)g,
        (__attribute__((address_space(3))) void*)l, 16, 0, 0);
}

// ---------------------------------------------------------------------------
// Cast q_data/m_data f32 -> bf16, vectorized (8 elem/thread each).
// ---------------------------------------------------------------------------
__global__ __launch_bounds__(256) void cast_data(
    const float* __restrict__ qd, const float* __restrict__ md,
    __bf16* __restrict__ qdb, __bf16* __restrict__ mdb)
{
    const int i = blockIdx.x * 256 + threadIdx.x;   // 0..262143
    const f32x4* q4 = (const f32x4*)qd;
    const f32x4* m4 = (const f32x4*)md;
    f32x4 a = q4[2 * i], b = q4[2 * i + 1];
    bf16x8 o;
#pragma unroll
    for (int j = 0; j < 4; j++) { o[j] = f2bf(a[j]); o[4 + j] = f2bf(b[j]); }
    *(bf16x8*)&qdb[i * 8] = o;
    a = m4[2 * i]; b = m4[2 * i + 1];
#pragma unroll
    for (int j = 0; j < 4; j++) { o[j] = f2bf(a[j]); o[4 + j] = f2bf(b[j]); }
    *(bf16x8*)&mdb[i * 8] = o;
}

// ---------------------------------------------------------------------------
// Tiled transpose+cast of the five 512x512 weight matrices (z selects).
// out[n*512+a] = in[a*512+n] * scale  (qw gets 1/8 folded in)
// ---------------------------------------------------------------------------
__global__ __launch_bounds__(256) void transpose_cast(
    const float* __restrict__ qw, const float* __restrict__ kw,
    const float* __restrict__ vw, const float* __restrict__ gw,
    const float* __restrict__ ow,
    __bf16* __restrict__ qwt, __bf16* __restrict__ kwt,
    __bf16* __restrict__ vwt, __bf16* __restrict__ gwt,
    __bf16* __restrict__ owt)
{
    __shared__ float tile[64][65];
    const int z = blockIdx.z;
    const float* src = (z == 0) ? qw : (z == 1) ? kw : (z == 2) ? vw : (z == 3) ? gw : ow;
    __bf16* dst = (z == 0) ? qwt : (z == 1) ? kwt : (z == 2) ? vwt : (z == 3) ? gwt : owt;
    const float scale = (z == 0) ? 0.125f : 1.0f;
    const int a0 = blockIdx.x * 64, n0 = blockIdx.y * 64;
    const int t = threadIdx.x, tr = t >> 4, tc = (t & 15) * 4;
#pragma unroll
    for (int ii = 0; ii < 4; ii++) {
        f32x4 v = *(const f32x4*)&src[(a0 + tr + 16 * ii) * 512 + n0 + tc];
#pragma unroll
        for (int j = 0; j < 4; j++) tile[tr + 16 * ii][tc + j] = v[j] * scale;
    }
    __syncthreads();
#pragma unroll
    for (int ii = 0; ii < 4; ii++) {
        const int nr = tr + 16 * ii;
        bf16x4 o;
#pragma unroll
        for (int j = 0; j < 4; j++) o[j] = f2bf(tile[tc + j][nr]);
        *(bf16x4*)&dst[(n0 + nr) * 512 + a0 + tc] = o;
    }
}

// ---------------------------------------------------------------------------
// 64x64-tile bf16 GEMM core, K=512 (kept for out_gemm where grid is small).
// ---------------------------------------------------------------------------
static __device__ __forceinline__ void gemm_core64(
    const __bf16* __restrict__ A, const __bf16* __restrict__ Bt,
    __bf16* As, __bf16* Bs, int m0, int n0, int t, f32x4 acc[4])
{
    const int w = t >> 6, quad = (t >> 4) & 3, col = t & 15;
    const int sr = t >> 2, sc = (t & 3) * 8;
    for (int kk = 0; kk < 512; kk += 32) {
        __syncthreads();
        async16(&A[(m0 + sr) * 512 + kk + sc], &As[w * 512]);
        async16(&Bt[(n0 + sr) * 512 + kk + sc], &Bs[w * 512]);
        __syncthreads();
        bf16x8 af = *(const bf16x8*)&As[(w * 16 + col) * 32 + quad * 8];
#pragma unroll
        for (int ns = 0; ns < 4; ns++) {
            bf16x8 bfr = *(const bf16x8*)&Bs[(ns * 16 + col) * 32 + quad * 8];
            acc[ns] = __builtin_amdgcn_mfma_f32_16x16x32_bf16(af, bfr, acc[ns], 0, 0, 0);
        }
    }
}

// ---------------------------------------------------------------------------
// 128x128-tile bf16 GEMM core, K=512 (m97 structure).
// ---------------------------------------------------------------------------
static __device__ __forceinline__ void gemm_core128(
    const __bf16* __restrict__ A, const __bf16* __restrict__ Bt,
    __bf16* As, __bf16* Bs, int m0, int n0, int t, f32x4 acc[4][4])
{
    const int w = t >> 6, quad = (t >> 4) & 3, col = t & 15;
    const int wr = (w >> 1) * 64, wc = (w & 1) * 64;
    const int sr = t >> 2, sc = (t & 3) * 8;   // staging: 64 rows x 4 chunks per call
    for (int kk = 0; kk < 512; kk += 32) {
        __syncthreads();
        async16(&A[(m0 + sr) * 512 + kk + sc], &As[w * 512]);
        async16(&A[(m0 + 64 + sr) * 512 + kk + sc], &As[2048 + w * 512]);
        async16(&Bt[(n0 + sr) * 512 + kk + sc], &Bs[w * 512]);
        async16(&Bt[(n0 + 64 + sr) * 512 + kk + sc], &Bs[2048 + w * 512]);
        __syncthreads();
        bf16x8 af[4], bfr[4];
#pragma unroll
        for (int i = 0; i < 4; i++)
            af[i] = *(const bf16x8*)&As[(wr + i * 16 + col) * 32 + quad * 8];
#pragma unroll
        for (int i = 0; i < 4; i++)
            bfr[i] = *(const bf16x8*)&Bs[(wc + i * 16 + col) * 32 + quad * 8];
#pragma unroll
        for (int mi = 0; mi < 4; mi++)
#pragma unroll
            for (int ni = 0; ni < 4; ni++)
                acc[mi][ni] = __builtin_amdgcn_mfma_f32_16x16x32_bf16(
                    af[mi], bfr[ni], acc[mi][ni], 0, 0, 0);
    }
}

// ---------------------------------------------------------------------------
// Merged projection GEMMs (128x128 tiles): z=0 q (b,h,pos,c); z=1 k;
// z=2 v transposed (b,h,c,pos); z=3 gate sigmoid (m,512).
// ---------------------------------------------------------------------------
__global__ __launch_bounds__(256) void proj_gemm(
    const __bf16* __restrict__ qdb, const __bf16* __restrict__ mdb,
    const __bf16* __restrict__ qwt, const __bf16* __restrict__ kwt,
    const __bf16* __restrict__ vwt, const __bf16* __restrict__ gwt,
    __bf16* __restrict__ qbuf, __bf16* __restrict__ kbuf,
    __bf16* __restrict__ vt, __bf16* __restrict__ gate,
    const float* __restrict__ gb)
{
    __shared__ __attribute__((aligned(16))) __bf16 As[4096];
    __shared__ __attribute__((aligned(16))) __bf16 Bs[4096];
    const int z = blockIdx.z;
    const __bf16* A = (z == 0 || z == 3) ? qdb : mdb;
    const __bf16* Bt = (z == 0) ? qwt : (z == 1) ? kwt : (z == 2) ? vwt : gwt;
    const int m0 = blockIdx.x * 128, n0 = blockIdx.y * 128;
    f32x4 acc[4][4];
#pragma unroll
    for (int i = 0; i < 4; i++)
#pragma unroll
        for (int j = 0; j < 4; j++) acc[i][j] = (f32x4){0.f, 0.f, 0.f, 0.f};
    gemm_core128(A, Bt, As, Bs, m0, n0, threadIdx.x, acc);

    const int t = threadIdx.x, w = t >> 6, quad = (t >> 4) & 3, col = t & 15;
    const int wr = (w >> 1) * 64, wc = (w & 1) * 64;
#pragma unroll
    for (int mi = 0; mi < 4; mi++) {
#pragma unroll
        for (int ni = 0; ni < 4; ni++) {
            const int ncol = n0 + wc + ni * 16 + col;
#pragma unroll
            for (int r = 0; r < 4; r++) {
                const int m = m0 + wr + mi * 16 + quad * 4 + r;
                const float v = acc[mi][ni][r];
                if (z <= 1) {
                    int b = m >> 10, pos = m & 1023, hh = ncol >> 6, c = ncol & 63;
                    __bf16* o = z ? kbuf : qbuf;
                    o[(((b * 8 + hh) * 1024 + pos) << 6) + c] = f2bf(v);
                } else if (z == 2) {
                    int b = m >> 10, pos = m & 1023, hh = ncol >> 6, c = ncol & 63;
                    vt[((((b * 8 + hh) << 6) + c) << 10) + pos] = f2bf(v);
                } else {
                    float g = 1.0f / (1.0f + __expf(-(v + gb[ncol])));
                    gate[m * 512 + ncol] = f2bf(g);
                }
            }
        }
    }
}

// ---------------------------------------------------------------------------
// Output GEMM: out[m,n] = wavg @ ow_t + output_b  (f32 out)
// ---------------------------------------------------------------------------
__global__ __launch_bounds__(256) void out_gemm(
    const __bf16* __restrict__ A, const __bf16* __restrict__ Bt,
    float* __restrict__ outp, const float* __restrict__ bvec)
{
    __shared__ __attribute__((aligned(16))) __bf16 As[2048];
    __shared__ __attribute__((aligned(16))) __bf16 Bs[2048];
    const int m0 = blockIdx.x * 64, n0 = blockIdx.y * 64;
    f32x4 acc[4];
#pragma unroll
    for (int i = 0; i < 4; i++) acc[i] = (f32x4){0.f, 0.f, 0.f, 0.f};
    gemm_core64(A, Bt, As, Bs, m0, n0, threadIdx.x, acc);

    const int t = threadIdx.x, w = t >> 6, quad = (t >> 4) & 3, col = t & 15;
    const int mrow0 = m0 + w * 16 + quad * 4;
#pragma unroll
    for (int ns = 0; ns < 4; ns++) {
        const int ncol = n0 + ns * 16 + col;
#pragma unroll
        for (int r = 0; r < 4; r++)
            outp[(mrow0 + r) * 512 + ncol] = acc[ns][r] + bvec[ncol];
    }
}

// ---------------------------------------------------------------------------
// Attention, max-free flash (R2 structure: best measured 263.1us) + T1
// XCD-aware block swizzle: 1D grid of 512; XCD c owns bh in [c*4, c*4+4)
// so each XCD's L2 holds only 4 bh's K/V (2 MiB) instead of all 32
// replicated -> removes 8x L2-fill replication of the shared K/V panels.
//  - counted-vmcnt barrier (T3/T4): end-of-iter waits only the 4 prefetch
//    global_load_lds; logit stores + nb loads stay in flight.
//  - bias staged to LDS once; s_setprio(1) around MFMA clusters (T5).
// ---------------------------------------------------------------------------
__global__ __launch_bounds__(256) void attn_kernel(
    const __bf16* __restrict__ qb, const __bf16* __restrict__ kb,
    const __bf16* __restrict__ vt, const float* __restrict__ bias,
    const float* __restrict__ nb, const __bf16* __restrict__ gate,
    float* __restrict__ logits_out, __bf16* __restrict__ wout)
{
    __shared__ __attribute__((aligned(16))) __bf16 ks[2][4096];
    __shared__ __attribute__((aligned(16))) __bf16 vs[2][4096];
    __shared__ __attribute__((aligned(16))) __bf16 ps[4][1152];   // 16 rows x 72 (pad)
    __shared__ __attribute__((aligned(16))) float bs[1024];       // bias row for this b

    // T1 swizzle: id -> (xcd = id&7) owns bh = xcd*4 + (sub>>4), qx = sub&15
    const int id = blockIdx.x;
    const int sub = id >> 3;
    const int bh = (id & 7) * 4 + (sub >> 4);
    const int q0 = (sub & 15) * 64;
    const int b = bh >> 3, h = bh & 7;
    const int t = threadIdx.x, lane = t & 63, w = t >> 6;
    const int quad = lane >> 4, col = lane & 15;

    const __bf16* kg = kb + bh * 65536;
    const __bf16* vg = vt + bh * 65536;
    float* lg = logits_out + (size_t)(bh * 1024 + q0) * 1024;
    const float* nbg = nb + (size_t)(h * 1024 + q0) * 1024;
    const float* biasg = bias + b * 1024;

    // staging geometry: thread t stages 16B chunk t (row r0, chunk c0), with
    // XOR swizzle: LDS chunk (r,c) holds global chunk c^(r&7) of row r.
    const int r0 = t >> 3, c0 = t & 7;
    const int sw = ((c0 ^ (r0 & 7)) << 3);

    async16(&kg[r0 * 64 + sw], &ks[0][w * 512]);
    async16(&kg[(r0 + 32) * 64 + sw], &ks[0][2048 + w * 512]);
    async16(&vg[r0 * 1024 + sw], &vs[0][w * 512]);
    async16(&vg[(r0 + 32) * 1024 + sw], &vs[0][2048 + w * 512]);
    async16(&biasg[lane * 4], (char*)bs + w * 1024);   // 4KB bias -> LDS, linear

    // loop-invariant q fragments, straight from global (no LDS round-trip)
    const __bf16* qrow = qb + (size_t)(bh * 1024 + q0 + w * 16 + col) * 64;
    const bf16x8 af0 = *(const bf16x8*)&qrow[quad * 8];
    const bf16x8 af1 = *(const bf16x8*)&qrow[32 + quad * 8];

    // nonbatched_bias prefetch pipeline (one k-block ahead)
    const float* nbrow = nbg + (w * 16 + quad * 4) * 1024 + col;
    float nbr[4][4];
#pragma unroll
    for (int ns = 0; ns < 4; ns++)
#pragma unroll
        for (int r = 0; r < 4; r++) nbr[ns][r] = nbrow[r * 1024 + ns * 16];

    f32x4 o_acc[4];
#pragma unroll
    for (int i = 0; i < 4; i++) o_acc[i] = (f32x4){0.f, 0.f, 0.f, 0.f};
    float lsum[4] = {0.f, 0.f, 0.f, 0.f};

    __bf16* pw = ps[w];
    // fragment-read swizzle: logical chunk (kst*4+quad) ^ (row&7), row&7 = col&7
    const int sw0 = ((quad ^ (col & 7)) << 3);
    const int sw1 = (((quad + 4) ^ (col & 7)) << 3);

    __syncthreads();    // one full drain: k0/v0/bias staged, then counted waits only

    for (int kbi = 0; kbi < 16; kbi++) {
        const int cur = kbi & 1;
        if (kbi < 15) {     // prefetch next tile into other buffer (oldest VMEM of iter)
            const int nx = cur ^ 1;
            const __bf16* kgn = kg + (kbi + 1) * 4096;
            const __bf16* vgn = vg + (kbi + 1) * 64;
            async16(&kgn[r0 * 64 + sw], &ks[nx][w * 512]);
            async16(&kgn[(r0 + 32) * 64 + sw], &ks[nx][2048 + w * 512]);
            async16(&vgn[r0 * 1024 + sw], &vs[nx][w * 512]);
            async16(&vgn[(r0 + 32) * 1024 + sw], &vs[nx][2048 + w * 512]);
        }
        __builtin_amdgcn_sched_barrier(0);   // pin prefetch issue before loads/stores below
        // issue next iteration's nb loads now; consumed after the barrier
        float nbrn[4][4];
        if (kbi < 15) {
#pragma unroll
            for (int ns = 0; ns < 4; ns++)
#pragma unroll
                for (int r = 0; r < 4; r++)
                    nbrn[ns][r] = nbrow[r * 1024 + ns * 16 + (kbi + 1) * 64];
        }
        const __bf16* kc = ks[cur];
        const __bf16* vc = vs[cur];

        // S = q @ k^T
        f32x4 s[4];
#pragma unroll
        for (int i = 0; i < 4; i++) s[i] = (f32x4){0.f, 0.f, 0.f, 0.f};
        __builtin_amdgcn_s_setprio(1);
#pragma unroll
        for (int ns = 0; ns < 4; ns++) {
            bf16x8 b0 = *(const bf16x8*)&kc[(ns * 16 + col) * 64 + sw0];
            s[ns] = __builtin_amdgcn_mfma_f32_16x16x32_bf16(af0, b0, s[ns], 0, 0, 0);
            bf16x8 b1 = *(const bf16x8*)&kc[(ns * 16 + col) * 64 + sw1];
            s[ns] = __builtin_amdgcn_mfma_f32_16x16x32_bf16(af1, b1, s[ns], 0, 0, 0);
        }
        __builtin_amdgcn_s_setprio(0);

        // max-free softmax: store raw logits, p = exp(raw + bias + nb)
        float* lrow = lg + (w * 16 + quad * 4) * 1024 + kbi * 64 + col;
#pragma unroll
        for (int ns = 0; ns < 4; ns++) {
            const float bval = bs[kbi * 64 + ns * 16 + col];   // LDS broadcast read
#pragma unroll
            for (int r = 0; r < 4; r++) {
                float raw = s[ns][r];
                __builtin_nontemporal_store(raw, &lrow[r * 1024 + ns * 16]);
                float p = __expf(raw + bval + nbr[ns][r]);
                lsum[r] += p;
                pw[(quad * 4 + r) * 72 + ns * 16 + col] = (__bf16)p;
            }
        }

        // O += P @ V
        bf16x8 pf0 = *(const bf16x8*)&pw[col * 72 + quad * 8];
        bf16x8 pf1 = *(const bf16x8*)&pw[col * 72 + 32 + quad * 8];
        __builtin_amdgcn_s_setprio(1);
#pragma unroll
        for (int ns = 0; ns < 4; ns++) {
            bf16x8 v0 = *(const bf16x8*)&vc[(ns * 16 + col) * 64 + sw0];
            o_acc[ns] = __builtin_amdgcn_mfma_f32_16x16x32_bf16(pf0, v0, o_acc[ns], 0, 0, 0);
            bf16x8 v1 = *(const bf16x8*)&vc[(ns * 16 + col) * 64 + sw1];
            o_acc[ns] = __builtin_amdgcn_mfma_f32_16x16x32_bf16(pf1, v1, o_acc[ns], 0, 0, 0);
        }
        __builtin_amdgcn_s_setprio(0);

        if (kbi < 15) {
#pragma unroll
            for (int ns = 0; ns < 4; ns++)
#pragma unroll
                for (int r = 0; r < 4; r++) nbr[ns][r] = nbrn[ns][r];
            // Counted-vmcnt barrier: wait own ds ops + the 4 prefetch
            // global_load_lds (oldest); leave logit stores + nb loads in
            // flight. All waves' prefetches complete => next tile readable.
            asm volatile("s_waitcnt lgkmcnt(0)" ::: "memory");
            asm volatile("s_waitcnt vmcnt(16)" ::: "memory");
            __builtin_amdgcn_sched_barrier(0);
            __builtin_amdgcn_s_barrier();
            __builtin_amdgcn_sched_barrier(0);
        }
    }

    // one deferred l-sum reduction across the 16 cols
#pragma unroll
    for (int mask = 1; mask < 16; mask <<= 1) {
#pragma unroll
        for (int r = 0; r < 4; r++) lsum[r] += __shfl_xor(lsum[r], mask);
    }
    float inv[4];
#pragma unroll
    for (int r = 0; r < 4; r++) inv[r] = 1.0f / lsum[r];

#pragma unroll
    for (int ns = 0; ns < 4; ns++) {
        const int c = ns * 16 + col;
#pragma unroll
        for (int r = 0; r < 4; r++) {
            const int pos = q0 + w * 16 + quad * 4 + r;
            float ov = o_acc[ns][r] * inv[r];
            float gv = (float)gate[(b * 1024 + pos) * 512 + h * 64 + c];
            wout[(b * 1024 + pos) * 512 + h * 64 + c] = f2bf(ov * gv);
        }
    }
}

// ---------------------------------------------------------------------------
extern "C" void kernel_launch(void* const* d_in, const int* in_sizes, int n_in,
                              void* d_out, int out_size, void* d_ws, size_t ws_size,
                              hipStream_t stream) {
    (void)in_sizes; (void)n_in; (void)out_size; (void)ws_size;
    const float* q_data   = (const float*)d_in[0];
    const float* m_data   = (const float*)d_in[1];
    const float* bias     = (const float*)d_in[2];
    const float* nbb      = (const float*)d_in[3];
    const float* query_w  = (const float*)d_in[4];
    const float* key_w    = (const float*)d_in[5];
    const float* value_w  = (const float*)d_in[6];
    const float* gating_w = (const float*)d_in[7];
    const float* gating_b = (const float*)d_in[8];
    const float* output_w = (const float*)d_in[9];
    const float* output_b = (const float*)d_in[10];

    char* ws = (char*)d_ws;
    __bf16* qd_b  = (__bf16*)(ws + 0);         // 4 MiB (reused as wavg later)
    __bf16* md_b  = (__bf16*)(ws + 4194304);   // 4 MiB
    __bf16* qw_t  = (__bf16*)(ws + 8388608);   // 512 KiB each
    __bf16* kw_t  = (__bf16*)(ws + 8912896);
    __bf16* vw_t  = (__bf16*)(ws + 9437184);
    __bf16* gw_t  = (__bf16*)(ws + 9961472);
    __bf16* ow_t  = (__bf16*)(ws + 10485760);
    __bf16* q_buf = (__bf16*)(ws + 11010048);  // 4 MiB (b,h,pos,c)
    __bf16* k_buf = (__bf16*)(ws + 15204352);  // 4 MiB (b,h,pos,c)
    __bf16* v_t   = (__bf16*)(ws + 19398656);  // 4 MiB (b,h,c,pos)
    __bf16* gate  = (__bf16*)(ws + 23592960);  // 4 MiB (m,512)
    __bf16* wavg  = (__bf16*)(ws + 0);         // overlays qd_b (dead by then)

    float* outp = (float*)d_out;
    float* logits = outp + (4 * 1024 * 512);

    cast_data<<<dim3(1024), dim3(256), 0, stream>>>(q_data, m_data, qd_b, md_b);
    transpose_cast<<<dim3(8, 8, 5), dim3(256), 0, stream>>>(
        query_w, key_w, value_w, gating_w, output_w, qw_t, kw_t, vw_t, gw_t, ow_t);
    proj_gemm<<<dim3(32, 4, 4), dim3(256), 0, stream>>>(
        qd_b, md_b, qw_t, kw_t, vw_t, gw_t, q_buf, k_buf, v_t, gate, gating_b);
    attn_kernel<<<dim3(512), dim3(256), 0, stream>>>(
        q_buf, k_buf, v_t, bias, nbb, gate, logits, wavg);
    out_gemm<<<dim3(64, 8), dim3(256), 0, stream>>>(wavg, ow_t, outp, output_b);
}

// Round 8
// 262.770 us; speedup vs baseline: 1.2715x; 1.0603x over previous
//
#include <hip/hip_runtime.h>
#include <hip/hip_bf16.h>

// B=4, Q=K=1024, C=512, H=8, HD=64, OUT=512
// d_out = [output (4*1024*512 f32) | logits_update (4*8*1024*1024 f32)]

typedef float f32x4 __attribute__((ext_vector_type(4)));
typedef __bf16 bf16x8 __attribute__((ext_vector_type(8)));
typedef __bf16 bf16x4 __attribute__((ext_vector_type(4)));

static __device__ __forceinline__ __bf16 f2bf(float x) {
    union { float f; unsigned int u; } c; c.f = x;
    unsigned int r = (c.u + 0x7fffu + ((c.u >> 16) & 1u)) >> 16;
    union { unsigned short s; __bf16 b; } o; o.s = (unsigned short)r;
    return o.b;
}

// async global->LDS, 16B per lane; LDS dest = wave-uniform base + lane*16
static __device__ __forceinline__ void async16(const void* g, void* l) {
    __builtin_amdgcn_global_load_lds(
        (const __attribute__((address_space(1))) void*)g,
        (__attribute__((address_space(3))) void*)l, 16, 0, 0);
}

// ---------------------------------------------------------------------------
// Cast q_data/m_data f32 -> bf16, vectorized (8 elem/thread each).
// ---------------------------------------------------------------------------
__global__ __launch_bounds__(256) void cast_data(
    const float* __restrict__ qd, const float* __restrict__ md,
    __bf16* __restrict__ qdb, __bf16* __restrict__ mdb)
{
    const int i = blockIdx.x * 256 + threadIdx.x;   // 0..262143
    const f32x4* q4 = (const f32x4*)qd;
    const f32x4* m4 = (const f32x4*)md;
    f32x4 a = q4[2 * i], b = q4[2 * i + 1];
    bf16x8 o;
#pragma unroll
    for (int j = 0; j < 4; j++) { o[j] = f2bf(a[j]); o[4 + j] = f2bf(b[j]); }
    *(bf16x8*)&qdb[i * 8] = o;
    a = m4[2 * i]; b = m4[2 * i + 1];
#pragma unroll
    for (int j = 0; j < 4; j++) { o[j] = f2bf(a[j]); o[4 + j] = f2bf(b[j]); }
    *(bf16x8*)&mdb[i * 8] = o;
}

// ---------------------------------------------------------------------------
// Tiled transpose+cast of the five 512x512 weight matrices (z selects).
// out[n*512+a] = in[a*512+n] * scale  (qw gets 1/8 folded in)
// ---------------------------------------------------------------------------
__global__ __launch_bounds__(256) void transpose_cast(
    const float* __restrict__ qw, const float* __restrict__ kw,
    const float* __restrict__ vw, const float* __restrict__ gw,
    const float* __restrict__ ow,
    __bf16* __restrict__ qwt, __bf16* __restrict__ kwt,
    __bf16* __restrict__ vwt, __bf16* __restrict__ gwt,
    __bf16* __restrict__ owt)
{
    __shared__ float tile[64][65];
    const int z = blockIdx.z;
    const float* src = (z == 0) ? qw : (z == 1) ? kw : (z == 2) ? vw : (z == 3) ? gw : ow;
    __bf16* dst = (z == 0) ? qwt : (z == 1) ? kwt : (z == 2) ? vwt : (z == 3) ? gwt : owt;
    const float scale = (z == 0) ? 0.125f : 1.0f;
    const int a0 = blockIdx.x * 64, n0 = blockIdx.y * 64;
    const int t = threadIdx.x, tr = t >> 4, tc = (t & 15) * 4;
#pragma unroll
    for (int ii = 0; ii < 4; ii++) {
        f32x4 v = *(const f32x4*)&src[(a0 + tr + 16 * ii) * 512 + n0 + tc];
#pragma unroll
        for (int j = 0; j < 4; j++) tile[tr + 16 * ii][tc + j] = v[j] * scale;
    }
    __syncthreads();
#pragma unroll
    for (int ii = 0; ii < 4; ii++) {
        const int nr = tr + 16 * ii;
        bf16x4 o;
#pragma unroll
        for (int j = 0; j < 4; j++) o[j] = f2bf(tile[tc + j][nr]);
        *(bf16x4*)&dst[(n0 + nr) * 512 + a0 + tc] = o;
    }
}

// ---------------------------------------------------------------------------
// 64x64-tile bf16 GEMM core, K=512 (kept for out_gemm where grid is small).
// ---------------------------------------------------------------------------
static __device__ __forceinline__ void gemm_core64(
    const __bf16* __restrict__ A, const __bf16* __restrict__ Bt,
    __bf16* As, __bf16* Bs, int m0, int n0, int t, f32x4 acc[4])
{
    const int w = t >> 6, quad = (t >> 4) & 3, col = t & 15;
    const int sr = t >> 2, sc = (t & 3) * 8;
    for (int kk = 0; kk < 512; kk += 32) {
        __syncthreads();
        async16(&A[(m0 + sr) * 512 + kk + sc], &As[w * 512]);
        async16(&Bt[(n0 + sr) * 512 + kk + sc], &Bs[w * 512]);
        __syncthreads();
        bf16x8 af = *(const bf16x8*)&As[(w * 16 + col) * 32 + quad * 8];
#pragma unroll
        for (int ns = 0; ns < 4; ns++) {
            bf16x8 bfr = *(const bf16x8*)&Bs[(ns * 16 + col) * 32 + quad * 8];
            acc[ns] = __builtin_amdgcn_mfma_f32_16x16x32_bf16(af, bfr, acc[ns], 0, 0, 0);
        }
    }
}

// ---------------------------------------------------------------------------
// 128x128-tile bf16 GEMM core, K=512 (m97 structure).
// ---------------------------------------------------------------------------
static __device__ __forceinline__ void gemm_core128(
    const __bf16* __restrict__ A, const __bf16* __restrict__ Bt,
    __bf16* As, __bf16* Bs, int m0, int n0, int t, f32x4 acc[4][4])
{
    const int w = t >> 6, quad = (t >> 4) & 3, col = t & 15;
    const int wr = (w >> 1) * 64, wc = (w & 1) * 64;
    const int sr = t >> 2, sc = (t & 3) * 8;   // staging: 64 rows x 4 chunks per call
    for (int kk = 0; kk < 512; kk += 32) {
        __syncthreads();
        async16(&A[(m0 + sr) * 512 + kk + sc], &As[w * 512]);
        async16(&A[(m0 + 64 + sr) * 512 + kk + sc], &As[2048 + w * 512]);
        async16(&Bt[(n0 + sr) * 512 + kk + sc], &Bs[w * 512]);
        async16(&Bt[(n0 + 64 + sr) * 512 + kk + sc], &Bs[2048 + w * 512]);
        __syncthreads();
        bf16x8 af[4], bfr[4];
#pragma unroll
        for (int i = 0; i < 4; i++)
            af[i] = *(const bf16x8*)&As[(wr + i * 16 + col) * 32 + quad * 8];
#pragma unroll
        for (int i = 0; i < 4; i++)
            bfr[i] = *(const bf16x8*)&Bs[(wc + i * 16 + col) * 32 + quad * 8];
#pragma unroll
        for (int mi = 0; mi < 4; mi++)
#pragma unroll
            for (int ni = 0; ni < 4; ni++)
                acc[mi][ni] = __builtin_amdgcn_mfma_f32_16x16x32_bf16(
                    af[mi], bfr[ni], acc[mi][ni], 0, 0, 0);
    }
}

// ---------------------------------------------------------------------------
// Merged projection GEMMs (128x128 tiles): z=0 q (b,h,pos,c); z=1 k;
// z=2 v transposed (b,h,c,pos); z=3 gate sigmoid (m,512).
// ---------------------------------------------------------------------------
__global__ __launch_bounds__(256) void proj_gemm(
    const __bf16* __restrict__ qdb, const __bf16* __restrict__ mdb,
    const __bf16* __restrict__ qwt, const __bf16* __restrict__ kwt,
    const __bf16* __restrict__ vwt, const __bf16* __restrict__ gwt,
    __bf16* __restrict__ qbuf, __bf16* __restrict__ kbuf,
    __bf16* __restrict__ vt, __bf16* __restrict__ gate,
    const float* __restrict__ gb)
{
    __shared__ __attribute__((aligned(16))) __bf16 As[4096];
    __shared__ __attribute__((aligned(16))) __bf16 Bs[4096];
    const int z = blockIdx.z;
    const __bf16* A = (z == 0 || z == 3) ? qdb : mdb;
    const __bf16* Bt = (z == 0) ? qwt : (z == 1) ? kwt : (z == 2) ? vwt : gwt;
    const int m0 = blockIdx.x * 128, n0 = blockIdx.y * 128;
    f32x4 acc[4][4];
#pragma unroll
    for (int i = 0; i < 4; i++)
#pragma unroll
        for (int j = 0; j < 4; j++) acc[i][j] = (f32x4){0.f, 0.f, 0.f, 0.f};
    gemm_core128(A, Bt, As, Bs, m0, n0, threadIdx.x, acc);

    const int t = threadIdx.x, w = t >> 6, quad = (t >> 4) & 3, col = t & 15;
    const int wr = (w >> 1) * 64, wc = (w & 1) * 64;
#pragma unroll
    for (int mi = 0; mi < 4; mi++) {
#pragma unroll
        for (int ni = 0; ni < 4; ni++) {
            const int ncol = n0 + wc + ni * 16 + col;
#pragma unroll
            for (int r = 0; r < 4; r++) {
                const int m = m0 + wr + mi * 16 + quad * 4 + r;
                const float v = acc[mi][ni][r];
                if (z <= 1) {
                    int b = m >> 10, pos = m & 1023, hh = ncol >> 6, c = ncol & 63;
                    __bf16* o = z ? kbuf : qbuf;
                    o[(((b * 8 + hh) * 1024 + pos) << 6) + c] = f2bf(v);
                } else if (z == 2) {
                    int b = m >> 10, pos = m & 1023, hh = ncol >> 6, c = ncol & 63;
                    vt[((((b * 8 + hh) << 6) + c) << 10) + pos] = f2bf(v);
                } else {
                    float g = 1.0f / (1.0f + __expf(-(v + gb[ncol])));
                    gate[m * 512 + ncol] = f2bf(g);
                }
            }
        }
    }
}

// ---------------------------------------------------------------------------
// Output GEMM: out[m,n] = wavg @ ow_t + output_b  (f32 out)
// ---------------------------------------------------------------------------
__global__ __launch_bounds__(256) void out_gemm(
    const __bf16* __restrict__ A, const __bf16* __restrict__ Bt,
    float* __restrict__ outp, const float* __restrict__ bvec)
{
    __shared__ __attribute__((aligned(16))) __bf16 As[2048];
    __shared__ __attribute__((aligned(16))) __bf16 Bs[2048];
    const int m0 = blockIdx.x * 64, n0 = blockIdx.y * 64;
    f32x4 acc[4];
#pragma unroll
    for (int i = 0; i < 4; i++) acc[i] = (f32x4){0.f, 0.f, 0.f, 0.f};
    gemm_core64(A, Bt, As, Bs, m0, n0, threadIdx.x, acc);

    const int t = threadIdx.x, w = t >> 6, quad = (t >> 4) & 3, col = t & 15;
    const int mrow0 = m0 + w * 16 + quad * 4;
#pragma unroll
    for (int ns = 0; ns < 4; ns++) {
        const int ncol = n0 + ns * 16 + col;
#pragma unroll
        for (int r = 0; r < 4; r++)
            outp[(mrow0 + r) * 512 + ncol] = acc[ns][r] + bvec[ncol];
    }
}

// ---------------------------------------------------------------------------
// Attention, max-free flash (R2 structure, best measured 263.1us) with two
// surgical deltas driven by R4/R6 counters (WRITE 177MB vs 132 mandatory,
// FETCH 82 vs 48 -> partial-line RMW on logit stores; barrier vmcnt(16)
// drains nb loads issued ~300cyc earlier at ~600cyc L3 latency):
//  1. logit stores grouped per row (r outer, ns inner, separate burst) so
//     the 4x64B segments of each 256B row-range issue back-to-back and
//     merge into full 128B lines (kills RMW amplification).
//  2. nb prefetched TWO k-blocks ahead (3 named register sets, static
//     indexing); barrier relaxed to vmcnt(32) = drains the 4 K/V
//     prefetches + previous-iter ops, leaves this iter's nb+stores in
//     flight. LDS/occupancy unchanged.
// ---------------------------------------------------------------------------
__global__ __launch_bounds__(256) void attn_kernel(
    const __bf16* __restrict__ qb, const __bf16* __restrict__ kb,
    const __bf16* __restrict__ vt, const float* __restrict__ bias,
    const float* __restrict__ nb, const __bf16* __restrict__ gate,
    float* __restrict__ logits_out, __bf16* __restrict__ wout)
{
    __shared__ __attribute__((aligned(16))) __bf16 ks[2][4096];
    __shared__ __attribute__((aligned(16))) __bf16 vs[2][4096];
    __shared__ __attribute__((aligned(16))) __bf16 ps[4][1152];   // 16 rows x 72 (pad)
    __shared__ __attribute__((aligned(16))) float bs[1024];       // bias row for this b

    const int bh = blockIdx.y, b = bh >> 3, h = bh & 7;
    const int q0 = blockIdx.x * 64;
    const int t = threadIdx.x, lane = t & 63, w = t >> 6;
    const int quad = lane >> 4, col = lane & 15;

    const __bf16* kg = kb + bh * 65536;
    const __bf16* vg = vt + bh * 65536;
    float* lg = logits_out + (size_t)(bh * 1024 + q0) * 1024;
    const float* nbg = nb + (size_t)(h * 1024 + q0) * 1024;
    const float* biasg = bias + b * 1024;

    // staging geometry: thread t stages 16B chunk t (row r0, chunk c0), with
    // XOR swizzle: LDS chunk (r,c) holds global chunk c^(r&7) of row r.
    const int r0 = t >> 3, c0 = t & 7;
    const int sw = ((c0 ^ (r0 & 7)) << 3);

    async16(&kg[r0 * 64 + sw], &ks[0][w * 512]);
    async16(&kg[(r0 + 32) * 64 + sw], &ks[0][2048 + w * 512]);
    async16(&vg[r0 * 1024 + sw], &vs[0][w * 512]);
    async16(&vg[(r0 + 32) * 1024 + sw], &vs[0][2048 + w * 512]);
    async16(&biasg[lane * 4], (char*)bs + w * 1024);   // 4KB bias -> LDS, linear

    // loop-invariant q fragments, straight from global (no LDS round-trip)
    const __bf16* qrow = qb + (size_t)(bh * 1024 + q0 + w * 16 + col) * 64;
    const bf16x8 af0 = *(const bf16x8*)&qrow[quad * 8];
    const bf16x8 af1 = *(const bf16x8*)&qrow[32 + quad * 8];

    // nonbatched_bias prefetch pipeline, TWO k-blocks ahead:
    // nbr0 = values for current kbi, nbr1 = kbi+1, nbrn = incoming kbi+2.
    const float* nbrow = nbg + (w * 16 + quad * 4) * 1024 + col;
    float nbr0[4][4], nbr1[4][4];
#pragma unroll
    for (int ns = 0; ns < 4; ns++)
#pragma unroll
        for (int r = 0; r < 4; r++) {
            nbr0[ns][r] = nbrow[r * 1024 + ns * 16];
            nbr1[ns][r] = nbrow[r * 1024 + ns * 16 + 64];
        }

    f32x4 o_acc[4];
#pragma unroll
    for (int i = 0; i < 4; i++) o_acc[i] = (f32x4){0.f, 0.f, 0.f, 0.f};
    float lsum[4] = {0.f, 0.f, 0.f, 0.f};

    __bf16* pw = ps[w];
    // fragment-read swizzle: logical chunk (kst*4+quad) ^ (row&7), row&7 = col&7
    const int sw0 = ((quad ^ (col & 7)) << 3);
    const int sw1 = (((quad + 4) ^ (col & 7)) << 3);

    __syncthreads();    // one full drain: k0/v0/bias staged, then counted waits only

    for (int kbi = 0; kbi < 16; kbi++) {
        const int cur = kbi & 1;
        if (kbi < 15) {     // prefetch next tile into other buffer (oldest VMEM of iter)
            const int nx = cur ^ 1;
            const __bf16* kgn = kg + (kbi + 1) * 4096;
            const __bf16* vgn = vg + (kbi + 1) * 64;
            async16(&kgn[r0 * 64 + sw], &ks[nx][w * 512]);
            async16(&kgn[(r0 + 32) * 64 + sw], &ks[nx][2048 + w * 512]);
            async16(&vgn[r0 * 1024 + sw], &vs[nx][w * 512]);
            async16(&vgn[(r0 + 32) * 1024 + sw], &vs[nx][2048 + w * 512]);
        }
        __builtin_amdgcn_sched_barrier(0);   // pin prefetch issue before loads/stores below
        // issue nb loads for kbi+2 now; consumed two barriers later
        float nbrn[4][4];
        if (kbi < 14) {
#pragma unroll
            for (int ns = 0; ns < 4; ns++)
#pragma unroll
                for (int r = 0; r < 4; r++)
                    nbrn[ns][r] = nbrow[r * 1024 + ns * 16 + (kbi + 2) * 64];
        }
        const __bf16* kc = ks[cur];
        const __bf16* vc = vs[cur];

        // S = q @ k^T
        f32x4 s[4];
#pragma unroll
        for (int i = 0; i < 4; i++) s[i] = (f32x4){0.f, 0.f, 0.f, 0.f};
        __builtin_amdgcn_s_setprio(1);
#pragma unroll
        for (int ns = 0; ns < 4; ns++) {
            bf16x8 b0 = *(const bf16x8*)&kc[(ns * 16 + col) * 64 + sw0];
            s[ns] = __builtin_amdgcn_mfma_f32_16x16x32_bf16(af0, b0, s[ns], 0, 0, 0);
            bf16x8 b1 = *(const bf16x8*)&kc[(ns * 16 + col) * 64 + sw1];
            s[ns] = __builtin_amdgcn_mfma_f32_16x16x32_bf16(af1, b1, s[ns], 0, 0, 0);
        }
        __builtin_amdgcn_s_setprio(0);

        // raw-logit store burst, grouped per row: the 4 ns-segments (4x64B)
        // of each row issue back-to-back -> full-line merge at TCC.
        float* lrow = lg + (w * 16 + quad * 4) * 1024 + kbi * 64 + col;
#pragma unroll
        for (int r = 0; r < 4; r++) {
#pragma unroll
            for (int ns = 0; ns < 4; ns++)
                __builtin_nontemporal_store(s[ns][r], &lrow[r * 1024 + ns * 16]);
        }

        // max-free softmax: p = exp(raw + bias + nb)
#pragma unroll
        for (int ns = 0; ns < 4; ns++) {
            const float bval = bs[kbi * 64 + ns * 16 + col];   // LDS broadcast read
#pragma unroll
            for (int r = 0; r < 4; r++) {
                float p = __expf(s[ns][r] + bval + nbr0[ns][r]);
                lsum[r] += p;
                pw[(quad * 4 + r) * 72 + ns * 16 + col] = (__bf16)p;
            }
        }

        // O += P @ V
        bf16x8 pf0 = *(const bf16x8*)&pw[col * 72 + quad * 8];
        bf16x8 pf1 = *(const bf16x8*)&pw[col * 72 + 32 + quad * 8];
        __builtin_amdgcn_s_setprio(1);
#pragma unroll
        for (int ns = 0; ns < 4; ns++) {
            bf16x8 v0 = *(const bf16x8*)&vc[(ns * 16 + col) * 64 + sw0];
            o_acc[ns] = __builtin_amdgcn_mfma_f32_16x16x32_bf16(pf0, v0, o_acc[ns], 0, 0, 0);
            bf16x8 v1 = *(const bf16x8*)&vc[(ns * 16 + col) * 64 + sw1];
            o_acc[ns] = __builtin_amdgcn_mfma_f32_16x16x32_bf16(pf1, v1, o_acc[ns], 0, 0, 0);
        }
        __builtin_amdgcn_s_setprio(0);

        // rotate nb register pipeline (static indices only)
#pragma unroll
        for (int ns = 0; ns < 4; ns++)
#pragma unroll
            for (int r = 0; r < 4; r++) {
                nbr0[ns][r] = nbr1[ns][r];
                nbr1[ns][r] = nbrn[ns][r];
            }

        if (kbi < 15) {
            // Counted-vmcnt barrier: newest 32 VMEM = {16 nb(kbi+2), 16
            // stores(kbi)}; waiting to 32 drains everything older, incl.
            // this iter's 4 K/V prefetches. nb(kbi+1) (drained too) has had
            // a full iteration of latency cover.
            asm volatile("s_waitcnt lgkmcnt(0)" ::: "memory");
            asm volatile("s_waitcnt vmcnt(32)" ::: "memory");
            __builtin_amdgcn_sched_barrier(0);
            __builtin_amdgcn_s_barrier();
            __builtin_amdgcn_sched_barrier(0);
        }
    }

    // one deferred l-sum reduction across the 16 cols
#pragma unroll
    for (int mask = 1; mask < 16; mask <<= 1) {
#pragma unroll
        for (int r = 0; r < 4; r++) lsum[r] += __shfl_xor(lsum[r], mask);
    }
    float inv[4];
#pragma unroll
    for (int r = 0; r < 4; r++) inv[r] = 1.0f / lsum[r];

#pragma unroll
    for (int ns = 0; ns < 4; ns++) {
        const int c = ns * 16 + col;
#pragma unroll
        for (int r = 0; r < 4; r++) {
            const int pos = q0 + w * 16 + quad * 4 + r;
            float ov = o_acc[ns][r] * inv[r];
            float gv = (float)gate[(b * 1024 + pos) * 512 + h * 64 + c];
            wout[(b * 1024 + pos) * 512 + h * 64 + c] = f2bf(ov * gv);
        }
    }
}

// ---------------------------------------------------------------------------
extern "C" void kernel_launch(void* const* d_in, const int* in_sizes, int n_in,
                              void* d_out, int out_size, void* d_ws, size_t ws_size,
                              hipStream_t stream) {
    (void)in_sizes; (void)n_in; (void)out_size; (void)ws_size;
    const float* q_data   = (const float*)d_in[0];
    const float* m_data   = (const float*)d_in[1];
    const float* bias     = (const float*)d_in[2];
    const float* nbb      = (const float*)d_in[3];
    const float* query_w  = (const float*)d_in[4];
    const float* key_w    = (const float*)d_in[5];
    const float* value_w  = (const float*)d_in[6];
    const float* gating_w = (const float*)d_in[7];
    const float* gating_b = (const float*)d_in[8];
    const float* output_w = (const float*)d_in[9];
    const float* output_b = (const float*)d_in[10];

    char* ws = (char*)d_ws;
    __bf16* qd_b  = (__bf16*)(ws + 0);         // 4 MiB (reused as wavg later)
    __bf16* md_b  = (__bf16*)(ws + 4194304);   // 4 MiB
    __bf16* qw_t  = (__bf16*)(ws + 8388608);   // 512 KiB each
    __bf16* kw_t  = (__bf16*)(ws + 8912896);
    __bf16* vw_t  = (__bf16*)(ws + 9437184);
    __bf16* gw_t  = (__bf16*)(ws + 9961472);
    __bf16* ow_t  = (__bf16*)(ws + 10485760);
    __bf16* q_buf = (__bf16*)(ws + 11010048);  // 4 MiB (b,h,pos,c)
    __bf16* k_buf = (__bf16*)(ws + 15204352);  // 4 MiB (b,h,pos,c)
    __bf16* v_t   = (__bf16*)(ws + 19398656);  // 4 MiB (b,h,c,pos)
    __bf16* gate  = (__bf16*)(ws + 23592960);  // 4 MiB (m,512)
    __bf16* wavg  = (__bf16*)(ws + 0);         // overlays qd_b (dead by then)

    float* outp = (float*)d_out;
    float* logits = outp + (4 * 1024 * 512);

    cast_data<<<dim3(1024), dim3(256), 0, stream>>>(q_data, m_data, qd_b, md_b);
    transpose_cast<<<dim3(8, 8, 5), dim3(256), 0, stream>>>(
        query_w, key_w, value_w, gating_w, output_w, qw_t, kw_t, vw_t, gw_t, ow_t);
    proj_gemm<<<dim3(32, 4, 4), dim3(256), 0, stream>>>(
        qd_b, md_b, qw_t, kw_t, vw_t, gw_t, q_buf, k_buf, v_t, gate, gating_b);
    attn_kernel<<<dim3(16, 32), dim3(256), 0, stream>>>(
        q_buf, k_buf, v_t, bias, nbb, gate, logits, wavg);
    out_gemm<<<dim3(64, 8), dim3(256), 0, stream>>>(wavg, ow_t, outp, output_b);
}